// Round 2
// baseline (950.714 us; speedup 1.0000x reference)
//
#include <hip/hip_runtime.h>
#include <cmath>

#define FILT 11
#define OT 32
#define ITL 42          // input tile rows (32 + 10)
#define SXP 44          // sx/sy row stride (16B-aligned)
#define HBP 36          // hb row stride (16B-aligned)

struct GW { float w[FILT]; };

// ---- order-preserving float<->uint encode for atomic min/max ----
__device__ __forceinline__ unsigned enc_f(float f) {
    unsigned u = __float_as_uint(f);
    return (u & 0x80000000u) ? ~u : (u | 0x80000000u);
}
__device__ __forceinline__ float dec_f(unsigned u) {
    return (u & 0x80000000u) ? __uint_as_float(u & 0x7FFFFFFFu)
                             : __uint_as_float(~u);
}

__global__ void init_acc(unsigned* ws) {
    int t = threadIdx.x;
    if (t == 0) { ws[0] = 0u; ws[1] = 0xFFFFFFFFu; }
    for (int i = 2 + t; i < 512; i += blockDim.x) ws[i] = 0u;  // float 0.0
}

__global__ void minmax_kernel(const float4* __restrict__ t, long n4, unsigned* mm) {
    unsigned mx = 0u, mn = 0xFFFFFFFFu;
    long stride = (long)gridDim.x * blockDim.x;
    for (long i = (long)blockIdx.x * blockDim.x + threadIdx.x; i < n4; i += stride) {
        float4 v = t[i];
        unsigned a = enc_f(v.x), b = enc_f(v.y), c = enc_f(v.z), d = enc_f(v.w);
        mx = max(mx, max(max(a, b), max(c, d)));
        mn = min(mn, min(min(a, b), min(c, d)));
    }
    for (int off = 32; off; off >>= 1) {
        mx = max(mx, (unsigned)__shfl_down((int)mx, off));
        mn = min(mn, (unsigned)__shfl_down((int)mn, off));
    }
    __shared__ unsigned smx[4], smn[4];
    int wid = threadIdx.x >> 6, lane = threadIdx.x & 63;
    if (lane == 0) { smx[wid] = mx; smn[wid] = mn; }
    __syncthreads();
    if (threadIdx.x == 0) {
        for (int i = 1; i < 4; i++) { mx = max(mx, smx[i]); mn = min(mn, smn[i]); }
        atomicMax(&mm[0], mx);
        atomicMin(&mm[1], mn);
    }
}

__global__ __launch_bounds__(256) void ssim_fused(
    const float* __restrict__ x, const float* __restrict__ y,
    int H, int W, int Ho, int Wo, int C,
    const unsigned* __restrict__ mm,
    float* __restrict__ cs_sum, float* __restrict__ ssim_sum, GW gw,
    float* __restrict__ poolx, float* __restrict__ pooly, int do_pool)
{
    __shared__ float sx[ITL][SXP];
    __shared__ float sy[ITL][SXP];
    __shared__ float hb[5][ITL][HBP];
    __shared__ float rcs[4], rss[4];

    const int tid = threadIdx.x;
    const int img = blockIdx.z;
    const int n = img / C;
    const int oy0 = blockIdx.y * OT;
    const int ox0 = blockIdx.x * OT;
    const float* xp = x + (size_t)img * H * W;
    const float* yp = y + (size_t)img * H * W;

    // ---- stage 42x44 (clamped) as float4 quads ----
    const bool fast = (ox0 + SXP <= W);
    for (int i = tid; i < ITL * (SXP / 4); i += 256) {  // 42*11 = 462
        int r = i / (SXP / 4), qd = i % (SXP / 4);
        int gr = min(oy0 + r, H - 1);
        const float* xr = xp + (size_t)gr * W;
        const float* yr = yp + (size_t)gr * W;
        float4 vx, vy;
        if (fast) {
            vx = *(const float4*)&xr[ox0 + 4 * qd];
            vy = *(const float4*)&yr[ox0 + 4 * qd];
        } else {
            int c0 = min(ox0 + 4 * qd + 0, W - 1), c1 = min(ox0 + 4 * qd + 1, W - 1);
            int c2 = min(ox0 + 4 * qd + 2, W - 1), c3 = min(ox0 + 4 * qd + 3, W - 1);
            vx = make_float4(xr[c0], xr[c1], xr[c2], xr[c3]);
            vy = make_float4(yr[c0], yr[c1], yr[c2], yr[c3]);
        }
        *(float4*)&sx[r][4 * qd] = vx;
        *(float4*)&sy[r][4 * qd] = vy;
    }
    __syncthreads();

    // ---- horizontal pass: 42 rows x 8 col-groups of 4 ----
    for (int i = tid; i < ITL * 8; i += 256) {
        int r = i >> 3, c0 = (i & 7) << 2;
        float xv[16], yv[16];
        ((float4*)xv)[0] = *(float4*)&sx[r][c0];
        ((float4*)xv)[1] = *(float4*)&sx[r][c0 + 4];
        ((float4*)xv)[2] = *(float4*)&sx[r][c0 + 8];
        ((float4*)xv)[3] = *(float4*)&sx[r][c0 + 12];
        ((float4*)yv)[0] = *(float4*)&sy[r][c0];
        ((float4*)yv)[1] = *(float4*)&sy[r][c0 + 4];
        ((float4*)yv)[2] = *(float4*)&sy[r][c0 + 8];
        ((float4*)yv)[3] = *(float4*)&sy[r][c0 + 12];
        float xx[14], yy[14], xy[14];
#pragma unroll
        for (int t = 0; t < 14; t++) {
            xx[t] = xv[t] * xv[t];
            yy[t] = yv[t] * yv[t];
            xy[t] = xv[t] * yv[t];
        }
        float h0[4], h1[4], h2[4], h3[4], h4[4];
#pragma unroll
        for (int j = 0; j < 4; j++) {
            float s0 = 0.f, s1 = 0.f, s2 = 0.f, s3 = 0.f, s4 = 0.f;
#pragma unroll
            for (int k = 0; k < FILT; k++) {
                float w = gw.w[k];
                s0 += w * xv[j + k];
                s1 += w * yv[j + k];
                s2 += w * xx[j + k];
                s3 += w * yy[j + k];
                s4 += w * xy[j + k];
            }
            h0[j] = s0; h1[j] = s1; h2[j] = s2; h3[j] = s3; h4[j] = s4;
        }
        *(float4*)&hb[0][r][c0] = *(float4*)h0;
        *(float4*)&hb[1][r][c0] = *(float4*)h1;
        *(float4*)&hb[2][r][c0] = *(float4*)h2;
        *(float4*)&hb[3][r][c0] = *(float4*)h3;
        *(float4*)&hb[4][r][c0] = *(float4*)h4;
    }
    __syncthreads();

    // ---- vertical pass (1 wave, rotated per block) + fused pool (another wave) ----
    float mv = dec_f(mm[0]) - dec_f(mm[1]);
    float c1c = (0.01f * mv) * (0.01f * mv);
    float c2c = (0.03f * mv) * (0.03f * mv);
    float lcs = 0.f, lss = 0.f;

    int bh = (blockIdx.x + blockIdx.y + blockIdx.z) & 3;
    int vt = tid ^ (bh << 6);

    if (vt < 64) {
        int jc = vt & 7, rg = vt >> 3;
        int c0 = jc << 2, r0 = rg << 2;
        float acc[5][4][4];
#pragma unroll
        for (int q = 0; q < 5; q++)
#pragma unroll
            for (int i = 0; i < 4; i++)
#pragma unroll
                for (int j = 0; j < 4; j++) acc[q][i][j] = 0.f;
#pragma unroll
        for (int q = 0; q < 5; q++) {
#pragma unroll
            for (int k = 0; k < 14; k++) {
                float4 v = *(float4*)&hb[q][r0 + k][c0];
#pragma unroll
                for (int i = 0; i < 4; i++) {
                    if (k - i >= 0 && k - i <= 10) {
                        float w = gw.w[k - i];
                        acc[q][i][0] += w * v.x;
                        acc[q][i][1] += w * v.y;
                        acc[q][i][2] += w * v.z;
                        acc[q][i][3] += w * v.w;
                    }
                }
            }
        }
#pragma unroll
        for (int i = 0; i < 4; i++) {
            int orow = oy0 + r0 + i;
#pragma unroll
            for (int j = 0; j < 4; j++) {
                int ocol = ox0 + c0 + j;
                if (orow < Ho && ocol < Wo) {
                    float m1 = acc[0][i][j], m2 = acc[1][i][j];
                    float exx = acc[2][i][j], eyy = acc[3][i][j], exy = acc[4][i][j];
                    float mu1sq = m1 * m1, mu2sq = m2 * m2, mu12 = m1 * m2;
                    float s1 = exx - mu1sq, s2 = eyy - mu2sq, s12 = exy - mu12;
                    float cs = __fdividef(2.f * s12 + c2c, s1 + s2 + c2c);
                    float ss = __fdividef(2.f * mu12 + c1c, mu1sq + mu2sq + c1c) * cs;
                    lcs += cs;
                    lss += ss;
                }
            }
        }
    } else if (do_pool && vt < 192) {
        int j = vt - 64;  // 0..127
        int Hp = H >> 1, Wp = W >> 1;
        size_t base = (size_t)img * Hp * Wp;
        int py0 = oy0 >> 1, px0 = ox0 >> 1;
#pragma unroll
        for (int s = 0; s < 2; s++) {
            int o = j + (s << 7);  // 0..255
            int pr = o >> 4, pc = o & 15;
            float2 ax = *(float2*)&sx[2 * pr][2 * pc];
            float2 bx = *(float2*)&sx[2 * pr + 1][2 * pc];
            poolx[base + (size_t)(py0 + pr) * Wp + (px0 + pc)] =
                0.25f * (ax.x + ax.y + bx.x + bx.y);
            float2 ay = *(float2*)&sy[2 * pr][2 * pc];
            float2 by = *(float2*)&sy[2 * pr + 1][2 * pc];
            pooly[base + (size_t)(py0 + pr) * Wp + (px0 + pc)] =
                0.25f * (ay.x + ay.y + by.x + by.y);
        }
    }

    // ---- block reduction ----
    for (int off = 32; off; off >>= 1) {
        lcs += __shfl_down(lcs, off);
        lss += __shfl_down(lss, off);
    }
    int wid = tid >> 6, lane = tid & 63;
    if (lane == 0) { rcs[wid] = lcs; rss[wid] = lss; }
    __syncthreads();
    if (tid == 0) {
        float tcs = rcs[0] + rcs[1] + rcs[2] + rcs[3];
        float tss = rss[0] + rss[1] + rss[2] + rss[3];
        atomicAdd(&cs_sum[n], tcs);
        atomicAdd(&ssim_sum[n], tss);
    }
}

__global__ void final_kernel(const float* __restrict__ cs_sum,
                             const float* __restrict__ ssim_sum,
                             float* __restrict__ out)
{
    const float cnt[5] = {3.f * 502 * 502, 3.f * 246 * 246, 3.f * 118 * 118,
                          3.f * 54 * 54, 3.f * 22 * 22};
    const float wts[5] = {0.0448f, 0.2856f, 0.3001f, 0.2363f, 0.1333f};
    int n = threadIdx.x;
    float ms = 0.f;
    if (n < 32) {
        float ssim = ssim_sum[4 * 32 + n] / cnt[4];
        float t = powf(ssim, wts[4]);
        ms = 1.f;
        for (int l = 0; l < 4; l++) {
            float cs = cs_sum[l * 32 + n] / cnt[l];
            ms *= powf(cs, wts[l]) * t;  // faithful: ssim^w4 inside the product
        }
    }
    for (int off = 32; off; off >>= 1) ms += __shfl_down(ms, off);
    if (threadIdx.x == 0) out[0] = ms / 32.f;
}

extern "C" void kernel_launch(void* const* d_in, const int* in_sizes, int n_in,
                              void* d_out, int out_size, void* d_ws, size_t ws_size,
                              hipStream_t stream) {
    const float* x0 = (const float*)d_in[0];
    const float* y0 = (const float*)d_in[1];
    float* out = (float*)d_out;
    float* ws = (float*)d_ws;
    unsigned* mm = (unsigned*)d_ws;
    float* cs_sum = ws + 2;
    float* ssim_sum = ws + 2 + 5 * 32;

    const int N = 32, C = 3;
    const int Hs[5] = {512, 256, 128, 64, 32};

    // pyramid buffers in ws (floats), after 512-float accumulator area
    float* wp = ws + 512;
    float* pxw[5] = {nullptr, nullptr, nullptr, nullptr, nullptr};
    float* pyw[5] = {nullptr, nullptr, nullptr, nullptr, nullptr};
    for (int l = 1; l < 5; l++) {
        size_t sz = (size_t)N * C * Hs[l] * Hs[l];
        pxw[l] = wp; wp += sz;
        pyw[l] = wp; wp += sz;
    }
    const float* px[5] = {x0, pxw[1], pxw[2], pxw[3], pxw[4]};
    const float* py[5] = {y0, pyw[1], pyw[2], pyw[3], pyw[4]};

    // gaussian weights (softmax of -c^2/(2*sigma^2))
    GW gw;
    {
        double tmp[FILT], s = 0.0;
        for (int k = 0; k < FILT; k++) {
            double c = (double)k - (FILT - 1) / 2.0;
            tmp[k] = exp(-c * c / (2.0 * 1.5 * 1.5));
            s += tmp[k];
        }
        for (int k = 0; k < FILT; k++) gw.w[k] = (float)(tmp[k] / s);
    }

    init_acc<<<1, 256, 0, stream>>>(mm);
    long n4 = (long)N * C * 512 * 512 / 4;
    minmax_kernel<<<1024, 256, 0, stream>>>((const float4*)y0, n4, mm);

    for (int l = 0; l < 5; l++) {
        int H = Hs[l], Ho = H - (FILT - 1);
        dim3 grid((H + OT - 1) / OT, (H + OT - 1) / OT, N * C);
        int do_pool = (l < 4) ? 1 : 0;
        ssim_fused<<<grid, 256, 0, stream>>>(px[l], py[l], H, H, Ho, Ho, C, mm,
                                             cs_sum + l * 32, ssim_sum + l * 32, gw,
                                             do_pool ? pxw[l + 1] : nullptr,
                                             do_pool ? pyw[l + 1] : nullptr, do_pool);
    }
    final_kernel<<<1, 64, 0, stream>>>(cs_sum, ssim_sum, out);
}